// Round 2
// baseline (1070.240 us; speedup 1.0000x reference)
//
#include <hip/hip_runtime.h>
#include <float.h>
#include <math.h>

#define TOKENS 8192
#define EXPERTS 256
#define HIDDEN 7168
#define TOPK 8
#define TOPKG 4
#define SCALE 2.5

#define BM 64
#define BN 64
#define BK 32

// logits[m][n] = dot(A[m][:], W[n][:]) with fp64 accumulation (fp32 inputs
// upcast once into LDS; fp32*fp32 is exact in double, sum error ~1e-10).
template <typename LogitT>
__global__ __launch_bounds__(256) void logits_gemm_f64(const float* __restrict__ A,
                                                       const float* __restrict__ W,
                                                       LogitT* __restrict__ out) {
    // K-major double tiles, XOR-swizzled on the M/N index (bits 2..5)
    __shared__ __align__(16) double As[BK * BM];
    __shared__ __align__(16) double Ws[BK * BN];

    const int tid  = threadIdx.x;
    const int row0 = blockIdx.x * BM;
    const int col0 = blockIdx.y * BN;
    const int tn = tid & 15;        // 0..15 -> 4 cols each
    const int tm = tid >> 4;        // 0..15 -> 4 rows each
    const int sr = tid >> 3;        // staging row 0..31 (and +32)
    const int sk = (tid & 7) << 2;  // staging k offset 0,4,...,28

    const float* Ap0 = A + (size_t)(row0 + sr) * HIDDEN + sk;
    const float* Ap1 = Ap0 + (size_t)32 * HIDDEN;
    const float* Wp0 = W + (size_t)(col0 + sr) * HIDDEN + sk;
    const float* Wp1 = Wp0 + (size_t)32 * HIDDEN;

    double acc[4][4] = {{0, 0, 0, 0}, {0, 0, 0, 0}, {0, 0, 0, 0}, {0, 0, 0, 0}};

    // prefetch tile 0 into registers
    float4 a0 = *(const float4*)(Ap0);
    float4 a1 = *(const float4*)(Ap1);
    float4 w0 = *(const float4*)(Wp0);
    float4 w1 = *(const float4*)(Wp1);

    for (int k0 = 0; k0 < HIDDEN; k0 += BK) {
        __syncthreads();  // previous tile's compute done
        #pragma unroll
        for (int j = 0; j < 4; ++j) {
            const int k  = sk + j;
            const int sw = (k & 15) << 2;
            As[k * BM + (sr ^ sw)]        = (double)((const float*)&a0)[j];
            As[k * BM + ((sr + 32) ^ sw)] = (double)((const float*)&a1)[j];
            Ws[k * BN + (sr ^ sw)]        = (double)((const float*)&w0)[j];
            Ws[k * BN + ((sr + 32) ^ sw)] = (double)((const float*)&w1)[j];
        }
        __syncthreads();

        // prefetch next tile while computing this one
        if (k0 + BK < HIDDEN) {
            a0 = *(const float4*)(Ap0 + k0 + BK);
            a1 = *(const float4*)(Ap1 + k0 + BK);
            w0 = *(const float4*)(Wp0 + k0 + BK);
            w1 = *(const float4*)(Wp1 + k0 + BK);
        }

        #pragma unroll
        for (int k = 0; k < BK; ++k) {
            const int sw = (k & 15) << 2;
            const double* ap = &As[k * BM + ((tm << 2) ^ sw)];
            const double* wp = &Ws[k * BN + ((tn << 2) ^ sw)];
            double av[4] = {ap[0], ap[1], ap[2], ap[3]};
            double wv[4] = {wp[0], wp[1], wp[2], wp[3]};
            #pragma unroll
            for (int i = 0; i < 4; ++i)
                #pragma unroll
                for (int j = 0; j < 4; ++j)
                    acc[i][j] = fma(av[i], wv[j], acc[i][j]);
        }
    }

    #pragma unroll
    for (int i = 0; i < 4; ++i) {
        const int row = row0 + (tm << 2) + i;
        LogitT* o = out + (size_t)row * EXPERTS + col0 + (tn << 2);
        #pragma unroll
        for (int j = 0; j < 4; ++j) o[j] = (LogitT)acc[i][j];
    }
}

// One wave (64 lanes) per token; lane holds experts 4*lane .. 4*lane+3.
// Group g = experts 32g..32g+31 = lanes 8g..8g+7. All math in fp64 so
// ranking decisions match an exact-arithmetic reference.
template <typename LogitT>
__global__ __launch_bounds__(256) void route_kernel_f64(const LogitT* __restrict__ logits,
                                                        const float* __restrict__ bias,
                                                        float* __restrict__ out) {
    const int lane = threadIdx.x & 63;
    const int wv   = threadIdx.x >> 6;
    const int t    = blockIdx.x * 4 + wv;

    const LogitT* lp = logits + (size_t)t * EXPERTS + (lane << 2);
    const double l0 = (double)lp[0], l1 = (double)lp[1];
    const double l2 = (double)lp[2], l3 = (double)lp[3];
    const float4 bzf = *(const float4*)(bias + (lane << 2));

    const double s0 = 1.0 / (1.0 + exp(-l0));
    const double s1 = 1.0 / (1.0 + exp(-l1));
    const double s2 = 1.0 / (1.0 + exp(-l2));
    const double s3 = 1.0 / (1.0 + exp(-l3));
    const double b0 = s0 + (double)bzf.x, b1 = s1 + (double)bzf.y;
    const double b2 = s2 + (double)bzf.z, b3 = s3 + (double)bzf.w;

    // top-2 of this lane's 4 biased scores
    double hi01 = fmax(b0, b1), lo01 = fmin(b0, b1);
    double hi23 = fmax(b2, b3), lo23 = fmin(b2, b3);
    double a0v = fmax(hi01, hi23);
    double a1v = fmax(fmin(hi01, hi23), fmax(lo01, lo23));
    // merge top-2 pairs across the 8 lanes of the group
    #pragma unroll
    for (int off = 1; off < 8; off <<= 1) {
        double o0 = __shfl_xor(a0v, off);
        double o1 = __shfl_xor(a1v, off);
        double n0 = fmax(a0v, o0);
        double n1 = fmax(fmin(a0v, o0), fmax(a1v, o1));
        a0v = n0; a1v = n1;
    }
    const double gscore = a0v + a1v;  // this lane's group score

    double gsc[8];
    #pragma unroll
    for (int g = 0; g < 8; ++g) gsc[g] = __shfl(gscore, g << 3);
    const int g0 = lane >> 3;
    int rank = 0;
    #pragma unroll
    for (int h = 0; h < 8; ++h)
        rank += ((gsc[h] > gscore) || ((gsc[h] == gscore) && (h < g0))) ? 1 : 0;
    const bool sel = (rank < TOPKG);  // stable top-4 groups (tie -> lower index)

    // masked biased scores: exactly 0.0 for non-selected groups
    double m0 = sel ? b0 : 0.0;
    double m1 = sel ? b1 : 0.0;
    double m2 = sel ? b2 : 0.0;
    double m3 = sel ? b3 : 0.0;

    double sum = 0.0;
    int myidx = 0; double mysc = 0.0;
    #pragma unroll
    for (int r = 0; r < TOPK; ++r) {
        // local argmax, tie -> lower slot
        double bv = m0; int bj = 0;
        if (m1 > bv) { bv = m1; bj = 1; }
        if (m2 > bv) { bv = m2; bj = 2; }
        if (m3 > bv) { bv = m3; bj = 3; }
        double bsc = (bj == 0) ? s0 : (bj == 1) ? s1 : (bj == 2) ? s2 : s3;
        int bidx = (lane << 2) | bj;
        // wave-wide argmax, tie -> lower expert index (matches jax.lax.top_k)
        #pragma unroll
        for (int off = 1; off < 64; off <<= 1) {
            double ov  = __shfl_xor(bv, off);
            int    oi  = __shfl_xor(bidx, off);
            double osc = __shfl_xor(bsc, off);
            if (ov > bv || (ov == bv && oi < bidx)) { bv = ov; bidx = oi; bsc = osc; }
        }
        sum += bsc;                       // raw-score sum for normalization
        if (lane == r) { myidx = bidx; mysc = bsc; }
        if ((bidx >> 2) == lane) {        // owner removes chosen expert
            const int sl = bidx & 3;
            if      (sl == 0) m0 = -DBL_MAX;
            else if (sl == 1) m1 = -DBL_MAX;
            else if (sl == 2) m2 = -DBL_MAX;
            else              m3 = -DBL_MAX;
        }
    }

    if (lane < TOPK) {
        const size_t base = (size_t)t * TOPK + lane;
        out[base] = (float)myidx;  // indices chunk (as float)
        out[(size_t)TOKENS * TOPK + base] =
            (float)(mysc / (sum + 1e-20) * SCALE);  // weights chunk
    }
}

extern "C" void kernel_launch(void* const* d_in, const int* in_sizes, int n_in,
                              void* d_out, int out_size, void* d_ws, size_t ws_size,
                              hipStream_t stream) {
    const float* hs   = (const float*)d_in[0];
    const float* wt   = (const float*)d_in[1];
    const float* bias = (const float*)d_in[2];
    float* out = (float*)d_out;

    dim3 grid(TOKENS / BM, EXPERTS / BN);  // 128 x 4
    const size_t need_f64 = (size_t)TOKENS * EXPERTS * sizeof(double);  // 16.8 MB

    if (ws_size >= need_f64) {
        double* logits = (double*)d_ws;
        logits_gemm_f64<double><<<grid, dim3(256), 0, stream>>>(hs, wt, logits);
        route_kernel_f64<double><<<TOKENS / 4, dim3(256), 0, stream>>>(logits, bias, out);
    } else {
        float* logits = (float*)d_ws;  // fallback: 8 MB scratch
        logits_gemm_f64<float><<<grid, dim3(256), 0, stream>>>(hs, wt, logits);
        route_kernel_f64<float><<<TOKENS / 4, dim3(256), 0, stream>>>(logits, bias, out);
    }
}

// Round 3
// 700.463 us; speedup vs baseline: 1.5279x; 1.5279x over previous
//
#include <hip/hip_runtime.h>
#include <float.h>
#include <math.h>

#define TOKENS 8192
#define EXPERTS 256
#define HIDDEN 7168
#define TOPK 8
#define TOPKG 4
#define NGROUP 8

#define BM 64
#define BN 64
#define BK 32
#define LDST 68  // LDS row stride (floats): bank = (4k + m)%32 -> conflict-free patterns

#define TAU_E 4.0e-6f   // expert-rank margin threshold (score space)
#define TAU_G 8.0e-6f   // group-selection margin threshold

// ws layout: [0, 8MB) f32 logits | [8MB, +4) counter | then token list
#define CNT_OFF  ((size_t)TOKENS * EXPERTS)           // in floats
#define LIST_OFF (CNT_OFF + 64)                       // in floats (256B pad)

__global__ void init_ws(int* cnt) {
    if (threadIdx.x == 0) *cnt = 0;
}

// ---------------- fast fp32 GEMM with periodic fp64 promotion ----------------
// logits[m][n] = dot(A[m][:], W[n][:]); fp32 inner accum, promoted to fp64
// every 2 K-tiles (64 steps) -> logit error sigma ~5e-7.
__global__ __launch_bounds__(256, 2) void logits_gemm_f32(const float* __restrict__ A,
                                                          const float* __restrict__ W,
                                                          float* __restrict__ out) {
    __shared__ __align__(16) float As[BK * LDST];
    __shared__ __align__(16) float Ws[BK * LDST];

    const int tid  = threadIdx.x;
    const int row0 = blockIdx.x * BM;
    const int col0 = blockIdx.y * BN;
    const int kq = tid & 3;    // k-quarter: offsets kq*4 and kq*4+16
    const int r  = tid >> 2;   // tile row 0..63
    const int tn = tid & 15;   // output col group (4 cols)
    const int tm = tid >> 4;   // output row group (4 rows)

    const float* Ap = A + (size_t)(row0 + r) * HIDDEN + (kq << 2);
    const float* Wp = W + (size_t)(col0 + r) * HIDDEN + (kq << 2);

    float  acc[4][4]   = {{0.f,0.f,0.f,0.f},{0.f,0.f,0.f,0.f},{0.f,0.f,0.f,0.f},{0.f,0.f,0.f,0.f}};
    double acc64[4][4] = {{0,0,0,0},{0,0,0,0},{0,0,0,0},{0,0,0,0}};

    float4 a0 = *(const float4*)(Ap);
    float4 a1 = *(const float4*)(Ap + 16);
    float4 w0 = *(const float4*)(Wp);
    float4 w1 = *(const float4*)(Wp + 16);

    const int NT = HIDDEN / BK;  // 224
    for (int t = 0; t < NT; ++t) {
        __syncthreads();
        const int kb = kq << 2;
        #pragma unroll
        for (int j = 0; j < 4; ++j) {
            As[(kb + j) * LDST + r]      = ((const float*)&a0)[j];
            As[(kb + 16 + j) * LDST + r] = ((const float*)&a1)[j];
            Ws[(kb + j) * LDST + r]      = ((const float*)&w0)[j];
            Ws[(kb + 16 + j) * LDST + r] = ((const float*)&w1)[j];
        }
        __syncthreads();

        if (t + 1 < NT) {
            const int kn = (t + 1) * BK;
            a0 = *(const float4*)(Ap + kn);
            a1 = *(const float4*)(Ap + kn + 16);
            w0 = *(const float4*)(Wp + kn);
            w1 = *(const float4*)(Wp + kn + 16);
        }

        #pragma unroll
        for (int k = 0; k < BK; ++k) {
            const float4 av = *(const float4*)&As[k * LDST + (tm << 2)];
            const float4 wv = *(const float4*)&Ws[k * LDST + (tn << 2)];
            const float* ap = (const float*)&av;
            const float* wp = (const float*)&wv;
            #pragma unroll
            for (int i = 0; i < 4; ++i)
                #pragma unroll
                for (int j = 0; j < 4; ++j)
                    acc[i][j] = fmaf(ap[i], wp[j], acc[i][j]);
        }

        if (t & 1) {  // promote every 64 k-steps
            #pragma unroll
            for (int i = 0; i < 4; ++i)
                #pragma unroll
                for (int j = 0; j < 4; ++j) {
                    acc64[i][j] += (double)acc[i][j];
                    acc[i][j] = 0.f;
                }
        }
    }
    #pragma unroll
    for (int i = 0; i < 4; ++i)  // harmless if already promoted (adds 0)
        #pragma unroll
        for (int j = 0; j < 4; ++j) acc64[i][j] += (double)acc[i][j];

    #pragma unroll
    for (int i = 0; i < 4; ++i) {
        const int row = row0 + (tm << 2) + i;
        float4 o = make_float4((float)acc64[i][0], (float)acc64[i][1],
                               (float)acc64[i][2], (float)acc64[i][3]);
        *(float4*)(out + (size_t)row * EXPERTS + col0 + (tn << 2)) = o;
    }
}

// ---------------- fast route with decision margins ----------------
// One wave per token. Trust fp32 decisions only when every ranking margin
// exceeds tau; otherwise flag the token for exact fp64 fallback.
__global__ __launch_bounds__(256) void route_margin(const float* __restrict__ logits,
                                                    const float* __restrict__ bias,
                                                    float* __restrict__ out,
                                                    int* __restrict__ cnt,
                                                    int* __restrict__ list) {
    const int lane = threadIdx.x & 63;
    const int t    = blockIdx.x * 4 + (threadIdx.x >> 6);

    const float4 lg = *(const float4*)(logits + (size_t)t * EXPERTS + (lane << 2));
    const float4 bz = *(const float4*)(bias + (lane << 2));

    const float s0 = 1.f / (1.f + expf(-lg.x));
    const float s1 = 1.f / (1.f + expf(-lg.y));
    const float s2 = 1.f / (1.f + expf(-lg.z));
    const float s3 = 1.f / (1.f + expf(-lg.w));
    const float b0 = s0 + bz.x, b1 = s1 + bz.y, b2 = s2 + bz.z, b3 = s3 + bz.w;

    // group score: sum of top-2 biased scores in the group (8 lanes/group)
    float hi01 = fmaxf(b0, b1), lo01 = fminf(b0, b1);
    float hi23 = fmaxf(b2, b3), lo23 = fminf(b2, b3);
    float a0v = fmaxf(hi01, hi23);
    float a1v = fmaxf(fminf(hi01, hi23), fmaxf(lo01, lo23));
    #pragma unroll
    for (int off = 1; off < 8; off <<= 1) {
        float o0 = __shfl_xor(a0v, off);
        float o1 = __shfl_xor(a1v, off);
        float n0 = fmaxf(a0v, o0);
        float n1 = fmaxf(fminf(a0v, o0), fmaxf(a1v, o1));
        a0v = n0; a1v = n1;
    }
    const float gscore = a0v + a1v;

    float gsc[8];
    #pragma unroll
    for (int g = 0; g < 8; ++g) gsc[g] = __shfl(gscore, g << 3);

    const int g0 = lane >> 3;
    int myrank = 0;
    float v4 = -1e30f, v5 = -1e30f;
    #pragma unroll
    for (int h = 0; h < 8; ++h) {
        int rk = 0;
        #pragma unroll
        for (int h2 = 0; h2 < 8; ++h2)
            rk += ((gsc[h2] > gsc[h]) || (gsc[h2] == gsc[h] && h2 < h)) ? 1 : 0;
        if (h == g0) myrank = rk;
        if (rk == TOPKG - 1) v4 = gsc[h];
        if (rk == TOPKG)     v5 = gsc[h];
    }
    const bool sel = (myrank < TOPKG);
    const float margin_g = v4 - v5;

    float m0 = sel ? b0 : 0.f;
    float m1 = sel ? b1 : 0.f;
    float m2 = sel ? b2 : 0.f;
    float m3 = sel ? b3 : 0.f;

    float sum = 0.f;
    int myidx = 0; float mysc = 0.f;
    float prev = 0.f, mine = 1e30f;
    #pragma unroll
    for (int rr = 0; rr < TOPK + 1; ++rr) {  // 9 ranks -> 8 margins
        float bv = m0; int bj = 0;
        if (m1 > bv) { bv = m1; bj = 1; }
        if (m2 > bv) { bv = m2; bj = 2; }
        if (m3 > bv) { bv = m3; bj = 3; }
        float bsc = (bj == 0) ? s0 : (bj == 1) ? s1 : (bj == 2) ? s2 : s3;
        int bidx = (lane << 2) | bj;
        #pragma unroll
        for (int off = 1; off < 64; off <<= 1) {
            float ov  = __shfl_xor(bv, off);
            int   oi  = __shfl_xor(bidx, off);
            float osc = __shfl_xor(bsc, off);
            if (ov > bv || (ov == bv && oi < bidx)) { bv = ov; bidx = oi; bsc = osc; }
        }
        if (rr) mine = fminf(mine, prev - bv);
        prev = bv;
        if (rr < TOPK) {
            sum += bsc;
            if (lane == rr) { myidx = bidx; mysc = bsc; }
            if ((bidx >> 2) == lane) {
                const int sl = bidx & 3;
                if      (sl == 0) m0 = -FLT_MAX;
                else if (sl == 1) m1 = -FLT_MAX;
                else if (sl == 2) m2 = -FLT_MAX;
                else              m3 = -FLT_MAX;
            }
        }
    }

    const bool fb = (margin_g < TAU_G) || (mine < TAU_E);
    if (fb) {
        if (lane == 0) { int p = atomicAdd(cnt, 1); list[p] = t; }
    } else if (lane < TOPK) {
        const size_t base = (size_t)t * TOPK + lane;
        out[base] = (float)myidx;
        out[(size_t)TOKENS * TOPK + base] = mysc / (sum + 1e-20f) * 2.5f;
    }
}

// ---------------- exact fp64 fallback for flagged tokens ----------------
__global__ __launch_bounds__(256) void fallback_exact(const float* __restrict__ A,
                                                      const float* __restrict__ W,
                                                      const float* __restrict__ bias,
                                                      const int* __restrict__ cnt,
                                                      const int* __restrict__ list,
                                                      float* __restrict__ out) {
    __shared__ float arow[HIDDEN];     // 28 KB
    __shared__ double lgs[EXPERTS];    // 2 KB
    const int tid = threadIdx.x;
    const int n = *cnt;

    for (int ti = blockIdx.x; ti < n; ti += gridDim.x) {
        const int t = list[ti];
        __syncthreads();
        for (int i = tid; i < HIDDEN / 4; i += 256)
            ((float4*)arow)[i] = ((const float4*)(A + (size_t)t * HIDDEN))[i];
        __syncthreads();

        // expert e = tid: exact-enough fp64 dot
        const float* wr = W + (size_t)tid * HIDDEN;
        double acc = 0.0;
        for (int k = 0; k < HIDDEN; k += 4) {
            const float4 w4 = *(const float4*)(wr + k);
            acc = fma((double)arow[k],     (double)w4.x, acc);
            acc = fma((double)arow[k + 1], (double)w4.y, acc);
            acc = fma((double)arow[k + 2], (double)w4.z, acc);
            acc = fma((double)arow[k + 3], (double)w4.w, acc);
        }
        lgs[tid] = acc;
        __syncthreads();

        if (tid < 64) {  // wave 0 routes this token exactly (fp64)
            const int lane = tid;
            const double l0 = lgs[(lane << 2)], l1 = lgs[(lane << 2) + 1];
            const double l2 = lgs[(lane << 2) + 2], l3 = lgs[(lane << 2) + 3];
            const float4 bzf = *(const float4*)(bias + (lane << 2));
            const double s0 = 1.0 / (1.0 + exp(-l0));
            const double s1 = 1.0 / (1.0 + exp(-l1));
            const double s2 = 1.0 / (1.0 + exp(-l2));
            const double s3 = 1.0 / (1.0 + exp(-l3));
            const double b0 = s0 + (double)bzf.x, b1 = s1 + (double)bzf.y;
            const double b2 = s2 + (double)bzf.z, b3 = s3 + (double)bzf.w;

            double hi01 = fmax(b0, b1), lo01 = fmin(b0, b1);
            double hi23 = fmax(b2, b3), lo23 = fmin(b2, b3);
            double a0v = fmax(hi01, hi23);
            double a1v = fmax(fmin(hi01, hi23), fmax(lo01, lo23));
            #pragma unroll
            for (int off = 1; off < 8; off <<= 1) {
                double o0 = __shfl_xor(a0v, off);
                double o1 = __shfl_xor(a1v, off);
                double n0 = fmax(a0v, o0);
                double n1 = fmax(fmin(a0v, o0), fmax(a1v, o1));
                a0v = n0; a1v = n1;
            }
            const double gscore = a0v + a1v;
            double gsc[8];
            #pragma unroll
            for (int g = 0; g < 8; ++g) gsc[g] = __shfl(gscore, g << 3);
            const int g0 = lane >> 3;
            int rank = 0;
            #pragma unroll
            for (int h = 0; h < 8; ++h)
                rank += ((gsc[h] > gscore) || (gsc[h] == gscore && h < g0)) ? 1 : 0;
            const bool sel = (rank < TOPKG);

            double m0 = sel ? b0 : 0.0;
            double m1 = sel ? b1 : 0.0;
            double m2 = sel ? b2 : 0.0;
            double m3 = sel ? b3 : 0.0;

            double sum = 0.0;
            int myidx = 0; double mysc = 0.0;
            #pragma unroll
            for (int rr = 0; rr < TOPK; ++rr) {
                double bv = m0; int bj = 0;
                if (m1 > bv) { bv = m1; bj = 1; }
                if (m2 > bv) { bv = m2; bj = 2; }
                if (m3 > bv) { bv = m3; bj = 3; }
                double bsc = (bj == 0) ? s0 : (bj == 1) ? s1 : (bj == 2) ? s2 : s3;
                int bidx = (lane << 2) | bj;
                #pragma unroll
                for (int off = 1; off < 64; off <<= 1) {
                    double ov  = __shfl_xor(bv, off);
                    int    oi  = __shfl_xor(bidx, off);
                    double osc = __shfl_xor(bsc, off);
                    if (ov > bv || (ov == bv && oi < bidx)) { bv = ov; bidx = oi; bsc = osc; }
                }
                sum += bsc;
                if (lane == rr) { myidx = bidx; mysc = bsc; }
                if ((bidx >> 2) == lane) {
                    const int sl = bidx & 3;
                    if      (sl == 0) m0 = -DBL_MAX;
                    else if (sl == 1) m1 = -DBL_MAX;
                    else if (sl == 2) m2 = -DBL_MAX;
                    else              m3 = -DBL_MAX;
                }
            }
            if (lane < TOPK) {
                const size_t base = (size_t)t * TOPK + lane;
                out[base] = (float)myidx;
                out[(size_t)TOKENS * TOPK + base] = (float)(mysc / (sum + 1e-20) * 2.5);
            }
        }
        __syncthreads();
    }
}

extern "C" void kernel_launch(void* const* d_in, const int* in_sizes, int n_in,
                              void* d_out, int out_size, void* d_ws, size_t ws_size,
                              hipStream_t stream) {
    const float* hs   = (const float*)d_in[0];
    const float* wt   = (const float*)d_in[1];
    const float* bias = (const float*)d_in[2];
    float* out    = (float*)d_out;
    float* logits = (float*)d_ws;
    int*   cnt    = (int*)((float*)d_ws + CNT_OFF);
    int*   list   = (int*)((float*)d_ws + LIST_OFF);

    init_ws<<<1, 64, 0, stream>>>(cnt);
    dim3 grid(TOKENS / BM, EXPERTS / BN);  // 128 x 4 = 512 blocks
    logits_gemm_f32<<<grid, dim3(256), 0, stream>>>(hs, wt, logits);
    route_margin<<<TOKENS / 4, dim3(256), 0, stream>>>(logits, bias, out, cnt, list);
    fallback_exact<<<256, dim3(256), 0, stream>>>(hs, wt, bias, cnt, list, out);
}

// Round 4
// 505.078 us; speedup vs baseline: 2.1190x; 1.3868x over previous
//
#include <hip/hip_runtime.h>
#include <float.h>
#include <math.h>

#define TOKENS 8192
#define EXPERTS 256
#define HIDDEN 7168
#define TOPK 8
#define TOPKG 4

#define BM 128
#define BN 64
#define BK 32
#define NKT (HIDDEN / BK)   // 224

#define TAU_E 2.0e-5f   // expert-rank margin threshold (score space)
#define TAU_G 3.0e-5f   // group-selection margin threshold

// ---- ws layout (bytes) ----
// [0, 8388608)          f32 logits [8192][256]
// [8388608, +256)       counter
// [8388864, +32768)     flagged-token list
// [8454144, +3670016)   Wh pre-split+pre-swizzled bf16 tiles [4 nb][224 kt][2048]
// [12124160, +3670016)  Wl same
#define CNT_B   8388608
#define LIST_B  8388864
#define WH_B    8454144
#define WL_B    12124160

typedef __attribute__((ext_vector_type(8))) short bf16x8;
typedef __attribute__((ext_vector_type(4))) float f32x4;

__device__ inline ushort bf16_rne(float x) {
    uint u = __float_as_uint(x);
    return (ushort)((u + 0x7FFFu + ((u >> 16) & 1u)) >> 16);
}
__device__ inline float bf16_tof(ushort h) {
    return __uint_as_float((uint)h << 16);
}
__device__ inline void split2(float x, ushort& h, ushort& l) {
    h = bf16_rne(x);
    l = bf16_rne(x - bf16_tof(h));
}
__device__ inline uint4 pack8(const ushort* s) {
    uint4 u;
    u.x = (uint)s[0] | ((uint)s[1] << 16);
    u.y = (uint)s[2] | ((uint)s[3] << 16);
    u.z = (uint)s[4] | ((uint)s[5] << 16);
    u.w = (uint)s[6] | ((uint)s[7] << 16);
    return u;
}

__global__ void init_ws(int* cnt) {
    if (threadIdx.x == 0) *cnt = 0;
}

// Pre-split W into bf16 hi/lo, stored in the EXACT swizzled LDS-tile image the
// GEMM stages linearly: tile (nb, kt) is 2048 ushorts; position p = r*32 + c
// holds element (r, k2 = c ^ (((r>>1)&3)<<3)).
__global__ __launch_bounds__(256) void split_w(const float* __restrict__ W,
                                               ushort* __restrict__ wh,
                                               ushort* __restrict__ wl) {
    const int tau = blockIdx.x * 256 + threadIdx.x;   // [0, 4*224*2048)
    const int nbkt = tau >> 11;
    const int p    = tau & 2047;
    const int nb   = nbkt / NKT;
    const int kt   = nbkt - nb * NKT;
    const int r    = p >> 5;
    const int c    = p & 31;
    const int k2   = c ^ (((r >> 1) & 3) << 3);
    const float w  = W[(size_t)(nb * 64 + r) * HIDDEN + kt * BK + k2];
    ushort h, l;
    split2(w, h, l);
    wh[tau] = h;
    wl[tau] = l;
}

// ---------------- bf16-split MFMA GEMM ----------------
// logits[m][n] = dot(A[m][:], W[n][:]) via 3 passes Ah*Wh + Al*Wh + Ah*Wl,
// fp32 MFMA accumulation. Logit error sigma ~1e-5 -> decisions guarded by
// route_margin's tau + exact fallback.
__global__ __launch_bounds__(256) void logits_mfma(const float* __restrict__ A,
                                                   const ushort* __restrict__ wh,
                                                   const ushort* __restrict__ wl,
                                                   float* __restrict__ out) {
    __shared__ ushort Ah[2][BM * BK];   // 8 KB each buf
    __shared__ ushort Al[2][BM * BK];
    __shared__ ushort Wh[2][BN * BK];   // 4 KB each buf
    __shared__ ushort Wl[2][BN * BK];

    const int b  = blockIdx.x;
    const int nb = (b & 7) >> 1;                  // XCD-pinned N-block
    const int mb = ((b >> 3) << 1) | (b & 1);
    const int row0 = mb * BM, col0 = nb * BN;

    const int t    = threadIdx.x;
    const int lane = t & 63;
    const int wid  = t >> 6;
    const int wm   = wid >> 1, wn = wid & 1;      // wave grid 2x2, wave tile 64x32

    // A staging map: thread t covers rows r0, r0+64; k-quarter q (8 floats)
    const int q  = t & 3;
    const int r0 = t >> 2;
    const float* Ap0 = A + (size_t)(row0 + r0) * HIDDEN + q * 8;
    const float* Ap1 = Ap0 + (size_t)64 * HIDDEN;
    const ushort* whT = wh + (size_t)nb * NKT * 2048;
    const ushort* wlT = wl + (size_t)nb * NKT * 2048;

    f32x4 acc[4][2];
    #pragma unroll
    for (int m = 0; m < 4; ++m)
        #pragma unroll
        for (int n = 0; n < 2; ++n) acc[m][n] = (f32x4)0.f;

    // staging registers
    float4 a00, a01, a10, a11;
    uint4 whr, wlr;

    // prologue: load kt=0
    a00 = *(const float4*)(Ap0);
    a01 = *(const float4*)(Ap0 + 4);
    a10 = *(const float4*)(Ap1);
    a11 = *(const float4*)(Ap1 + 4);
    whr = *(const uint4*)(whT + t * 8);
    wlr = *(const uint4*)(wlT + t * 8);

    const int sw0 = (r0 >> 1) & 3;          // swizzle bits for row r0
    const int sw1 = ((r0 + 64) >> 1) & 3;   // for row r0+64
    const int idxA0 = r0 * BK + ((q ^ sw0) << 3);
    const int idxA1 = (r0 + 64) * BK + ((q ^ sw1) << 3);

    // write staged regs -> buffer bb
    #define STAGE(bb)                                                         \
    do {                                                                      \
        ushort h8[8], l8[8];                                                  \
        const float* f0 = (const float*)&a00;                                 \
        const float* f1 = (const float*)&a01;                                 \
        _Pragma("unroll") for (int j = 0; j < 4; ++j) split2(f0[j], h8[j], l8[j]); \
        _Pragma("unroll") for (int j = 0; j < 4; ++j) split2(f1[j], h8[4+j], l8[4+j]); \
        *(uint4*)&Ah[bb][idxA0] = pack8(h8);                                  \
        *(uint4*)&Al[bb][idxA0] = pack8(l8);                                  \
        f0 = (const float*)&a10; f1 = (const float*)&a11;                     \
        _Pragma("unroll") for (int j = 0; j < 4; ++j) split2(f0[j], h8[j], l8[j]); \
        _Pragma("unroll") for (int j = 0; j < 4; ++j) split2(f1[j], h8[4+j], l8[4+j]); \
        *(uint4*)&Ah[bb][idxA1] = pack8(h8);                                  \
        *(uint4*)&Al[bb][idxA1] = pack8(l8);                                  \
        *(uint4*)&Wh[bb][t * 8] = whr;                                        \
        *(uint4*)&Wl[bb][t * 8] = wlr;                                        \
    } while (0)

    STAGE(0);

    // frag addressing
    const int fr = lane & 15;          // frag row/col within 16
    const int fg = lane >> 4;          // k-group 0..3

    for (int kt = 0; kt < NKT; ++kt) {
        const int bb = kt & 1;
        __syncthreads();   // buffer bb staged by all waves

        if (kt + 1 < NKT) {
            const int kn = (kt + 1) * BK;
            a00 = *(const float4*)(Ap0 + kn);
            a01 = *(const float4*)(Ap0 + kn + 4);
            a10 = *(const float4*)(Ap1 + kn);
            a11 = *(const float4*)(Ap1 + kn + 4);
            whr = *(const uint4*)(whT + (kt + 1) * 2048 + t * 8);
            wlr = *(const uint4*)(wlT + (kt + 1) * 2048 + t * 8);
        }

        // W fragments (B-operand): lane holds W[col = wn*32+nrep*16+fr][k = fg*8+j]
        bf16x8 wfh[2], wfl[2];
        #pragma unroll
        for (int n = 0; n < 2; ++n) {
            const int rw  = wn * 32 + n * 16 + fr;
            const int idx = rw * BK + (((fg) ^ ((rw >> 1) & 3)) << 3);
            wfh[n] = *(const bf16x8*)&Wh[bb][idx];
            wfl[n] = *(const bf16x8*)&Wl[bb][idx];
        }
        #pragma unroll
        for (int m = 0; m < 4; ++m) {
            const int ra  = wm * 64 + m * 16 + fr;
            const int idx = ra * BK + (((fg) ^ ((ra >> 1) & 3)) << 3);
            const bf16x8 afh = *(const bf16x8*)&Ah[bb][idx];
            const bf16x8 afl = *(const bf16x8*)&Al[bb][idx];
            #pragma unroll
            for (int n = 0; n < 2; ++n) {
                acc[m][n] = __builtin_amdgcn_mfma_f32_16x16x32_bf16(afh, wfh[n], acc[m][n], 0, 0, 0);
                acc[m][n] = __builtin_amdgcn_mfma_f32_16x16x32_bf16(afl, wfh[n], acc[m][n], 0, 0, 0);
                acc[m][n] = __builtin_amdgcn_mfma_f32_16x16x32_bf16(afh, wfl[n], acc[m][n], 0, 0, 0);
            }
        }

        if (kt + 1 < NKT) STAGE(bb ^ 1);
    }

    // epilogue: C/D layout col=lane&15, row=(lane>>4)*4+reg (m89-verified)
    const int cr = fg << 2;
    #pragma unroll
    for (int m = 0; m < 4; ++m)
        #pragma unroll
        for (int n = 0; n < 2; ++n)
            #pragma unroll
            for (int g = 0; g < 4; ++g)
                out[(size_t)(row0 + wm * 64 + m * 16 + cr + g) * EXPERTS +
                    (col0 + wn * 32 + n * 16 + fr)] = acc[m][n][g];
}

// ---------------- fast route with decision margins ----------------
__global__ __launch_bounds__(256) void route_margin(const float* __restrict__ logits,
                                                    const float* __restrict__ bias,
                                                    float* __restrict__ out,
                                                    int* __restrict__ cnt,
                                                    int* __restrict__ list) {
    const int lane = threadIdx.x & 63;
    const int t    = blockIdx.x * 4 + (threadIdx.x >> 6);

    const float4 lg = *(const float4*)(logits + (size_t)t * EXPERTS + (lane << 2));
    const float4 bz = *(const float4*)(bias + (lane << 2));

    const float s0 = 1.f / (1.f + expf(-lg.x));
    const float s1 = 1.f / (1.f + expf(-lg.y));
    const float s2 = 1.f / (1.f + expf(-lg.z));
    const float s3 = 1.f / (1.f + expf(-lg.w));
    const float b0 = s0 + bz.x, b1 = s1 + bz.y, b2 = s2 + bz.z, b3 = s3 + bz.w;

    float hi01 = fmaxf(b0, b1), lo01 = fminf(b0, b1);
    float hi23 = fmaxf(b2, b3), lo23 = fminf(b2, b3);
    float a0v = fmaxf(hi01, hi23);
    float a1v = fmaxf(fminf(hi01, hi23), fmaxf(lo01, lo23));
    #pragma unroll
    for (int off = 1; off < 8; off <<= 1) {
        float o0 = __shfl_xor(a0v, off);
        float o1 = __shfl_xor(a1v, off);
        float n0 = fmaxf(a0v, o0);
        float n1 = fmaxf(fminf(a0v, o0), fmaxf(a1v, o1));
        a0v = n0; a1v = n1;
    }
    const float gscore = a0v + a1v;

    float gsc[8];
    #pragma unroll
    for (int g = 0; g < 8; ++g) gsc[g] = __shfl(gscore, g << 3);

    const int g0 = lane >> 3;
    int myrank = 0;
    float v4 = -1e30f, v5 = -1e30f;
    #pragma unroll
    for (int h = 0; h < 8; ++h) {
        int rk = 0;
        #pragma unroll
        for (int h2 = 0; h2 < 8; ++h2)
            rk += ((gsc[h2] > gsc[h]) || (gsc[h2] == gsc[h] && h2 < h)) ? 1 : 0;
        if (h == g0) myrank = rk;
        if (rk == TOPKG - 1) v4 = gsc[h];
        if (rk == TOPKG)     v5 = gsc[h];
    }
    const bool sel = (myrank < TOPKG);
    const float margin_g = v4 - v5;

    float m0 = sel ? b0 : 0.f;
    float m1 = sel ? b1 : 0.f;
    float m2 = sel ? b2 : 0.f;
    float m3 = sel ? b3 : 0.f;

    float sum = 0.f;
    int myidx = 0; float mysc = 0.f;
    float prev = 0.f, mine = 1e30f;
    #pragma unroll
    for (int rr = 0; rr < TOPK + 1; ++rr) {
        float bv = m0; int bj = 0;
        if (m1 > bv) { bv = m1; bj = 1; }
        if (m2 > bv) { bv = m2; bj = 2; }
        if (m3 > bv) { bv = m3; bj = 3; }
        float bsc = (bj == 0) ? s0 : (bj == 1) ? s1 : (bj == 2) ? s2 : s3;
        int bidx = (lane << 2) | bj;
        #pragma unroll
        for (int off = 1; off < 64; off <<= 1) {
            float ov  = __shfl_xor(bv, off);
            int   oi  = __shfl_xor(bidx, off);
            float osc = __shfl_xor(bsc, off);
            if (ov > bv || (ov == bv && oi < bidx)) { bv = ov; bidx = oi; bsc = osc; }
        }
        if (rr) mine = fminf(mine, prev - bv);
        prev = bv;
        if (rr < TOPK) {
            sum += bsc;
            if (lane == rr) { myidx = bidx; mysc = bsc; }
            if ((bidx >> 2) == lane) {
                const int sl = bidx & 3;
                if      (sl == 0) m0 = -FLT_MAX;
                else if (sl == 1) m1 = -FLT_MAX;
                else if (sl == 2) m2 = -FLT_MAX;
                else              m3 = -FLT_MAX;
            }
        }
    }

    const bool fb = (margin_g < TAU_G) || (mine < TAU_E);
    if (fb) {
        if (lane == 0) { int p = atomicAdd(cnt, 1); list[p] = t; }
    } else if (lane < TOPK) {
        const size_t base = (size_t)t * TOPK + lane;
        out[base] = (float)myidx;
        out[(size_t)TOKENS * TOPK + base] = mysc / (sum + 1e-20f) * 2.5f;
    }
}

// ---------------- exact fp64 fallback for flagged tokens ----------------
__global__ __launch_bounds__(256) void fallback_exact(const float* __restrict__ A,
                                                      const float* __restrict__ W,
                                                      const float* __restrict__ bias,
                                                      const int* __restrict__ cnt,
                                                      const int* __restrict__ list,
                                                      float* __restrict__ out) {
    __shared__ float arow[HIDDEN];
    __shared__ double lgs[EXPERTS];
    const int tid = threadIdx.x;
    const int n = *cnt;

    for (int ti = blockIdx.x; ti < n; ti += gridDim.x) {
        const int t = list[ti];
        __syncthreads();
        for (int i = tid; i < HIDDEN / 4; i += 256)
            ((float4*)arow)[i] = ((const float4*)(A + (size_t)t * HIDDEN))[i];
        __syncthreads();

        const float* wr = W + (size_t)tid * HIDDEN;
        double acc = 0.0;
        for (int k = 0; k < HIDDEN; k += 4) {
            const float4 w4 = *(const float4*)(wr + k);
            acc = fma((double)arow[k],     (double)w4.x, acc);
            acc = fma((double)arow[k + 1], (double)w4.y, acc);
            acc = fma((double)arow[k + 2], (double)w4.z, acc);
            acc = fma((double)arow[k + 3], (double)w4.w, acc);
        }
        lgs[tid] = acc;
        __syncthreads();

        if (tid < 64) {
            const int lane = tid;
            const double l0 = lgs[(lane << 2)], l1 = lgs[(lane << 2) + 1];
            const double l2 = lgs[(lane << 2) + 2], l3 = lgs[(lane << 2) + 3];
            const float4 bzf = *(const float4*)(bias + (lane << 2));
            const double s0 = 1.0 / (1.0 + exp(-l0));
            const double s1 = 1.0 / (1.0 + exp(-l1));
            const double s2 = 1.0 / (1.0 + exp(-l2));
            const double s3 = 1.0 / (1.0 + exp(-l3));
            const double b0 = s0 + (double)bzf.x, b1 = s1 + (double)bzf.y;
            const double b2 = s2 + (double)bzf.z, b3 = s3 + (double)bzf.w;

            double hi01 = fmax(b0, b1), lo01 = fmin(b0, b1);
            double hi23 = fmax(b2, b3), lo23 = fmin(b2, b3);
            double a0v = fmax(hi01, hi23);
            double a1v = fmax(fmin(hi01, hi23), fmax(lo01, lo23));
            #pragma unroll
            for (int off = 1; off < 8; off <<= 1) {
                double o0 = __shfl_xor(a0v, off);
                double o1 = __shfl_xor(a1v, off);
                double n0 = fmax(a0v, o0);
                double n1 = fmax(fmin(a0v, o0), fmax(a1v, o1));
                a0v = n0; a1v = n1;
            }
            const double gscore = a0v + a1v;
            double gsc[8];
            #pragma unroll
            for (int g = 0; g < 8; ++g) gsc[g] = __shfl(gscore, g << 3);
            const int g0 = lane >> 3;
            int rank = 0;
            #pragma unroll
            for (int h = 0; h < 8; ++h)
                rank += ((gsc[h] > gscore) || (gsc[h] == gscore && h < g0)) ? 1 : 0;
            const bool sel = (rank < TOPKG);

            double m0 = sel ? b0 : 0.0;
            double m1 = sel ? b1 : 0.0;
            double m2 = sel ? b2 : 0.0;
            double m3 = sel ? b3 : 0.0;

            double sum = 0.0;
            int myidx = 0; double mysc = 0.0;
            #pragma unroll
            for (int rr = 0; rr < TOPK; ++rr) {
                double bv = m0; int bj = 0;
                if (m1 > bv) { bv = m1; bj = 1; }
                if (m2 > bv) { bv = m2; bj = 2; }
                if (m3 > bv) { bv = m3; bj = 3; }
                double bsc = (bj == 0) ? s0 : (bj == 1) ? s1 : (bj == 2) ? s2 : s3;
                int bidx = (lane << 2) | bj;
                #pragma unroll
                for (int off = 1; off < 64; off <<= 1) {
                    double ov  = __shfl_xor(bv, off);
                    int    oi  = __shfl_xor(bidx, off);
                    double osc = __shfl_xor(bsc, off);
                    if (ov > bv || (ov == bv && oi < bidx)) { bv = ov; bidx = oi; bsc = osc; }
                }
                sum += bsc;
                if (lane == rr) { myidx = bidx; mysc = bsc; }
                if ((bidx >> 2) == lane) {
                    const int sl = bidx & 3;
                    if      (sl == 0) m0 = -DBL_MAX;
                    else if (sl == 1) m1 = -DBL_MAX;
                    else if (sl == 2) m2 = -DBL_MAX;
                    else              m3 = -DBL_MAX;
                }
            }
            if (lane < TOPK) {
                const size_t base = (size_t)t * TOPK + lane;
                out[base] = (float)myidx;
                out[(size_t)TOKENS * TOPK + base] = (float)(mysc / (sum + 1e-20) * 2.5);
            }
        }
        __syncthreads();
    }
}

extern "C" void kernel_launch(void* const* d_in, const int* in_sizes, int n_in,
                              void* d_out, int out_size, void* d_ws, size_t ws_size,
                              hipStream_t stream) {
    const float* hs   = (const float*)d_in[0];
    const float* wt   = (const float*)d_in[1];
    const float* bias = (const float*)d_in[2];
    float* out = (float*)d_out;

    char* ws = (char*)d_ws;
    float*  logits = (float*)ws;
    int*    cnt    = (int*)(ws + CNT_B);
    int*    list   = (int*)(ws + LIST_B);
    ushort* wsh    = (ushort*)(ws + WH_B);
    ushort* wsl    = (ushort*)(ws + WL_B);

    init_ws<<<1, 64, 0, stream>>>(cnt);
    split_w<<<(4 * NKT * 2048) / 256, 256, 0, stream>>>(wt, wsh, wsl);
    logits_mfma<<<(TOKENS / BM) * (EXPERTS / BN), 256, 0, stream>>>(hs, wsh, wsl, logits);
    route_margin<<<TOKENS / 4, 256, 0, stream>>>(logits, bias, out, cnt, list);
    fallback_exact<<<256, 256, 0, stream>>>(hs, wt, bias, cnt, list, out);
}